// Round 6
// baseline (509.998 us; speedup 1.0000x reference)
//
#include <hip/hip_runtime.h>
#include <cfloat>

#define NTOK (64 * 4096)   // 262144 tokens
#define HID  128
#define NE   64
#define TK   6
#define BLK  256
#define TPT  2             // tokens per thread
#define GRID (NTOK / (BLK * TPT))   // 512 blocks -> 2 blocks/CU
#define WCOL 32            // LDS holds experts 32..63 only (16 KB)

// Per-token epilogue: top-6 -> outputs + cnt; acc[] -> softmax probs in place.
__device__ __forceinline__ void epilogue(float (&acc)[NE], int token,
                                         float* __restrict__ oidx,
                                         float* __restrict__ ow,
                                         unsigned int* cnt_s)
{
    float tv[TK];
    int   ti[TK];
#pragma unroll
    for (int q = 0; q < TK; ++q) { tv[q] = -FLT_MAX; ti[q] = 0; }

#pragma unroll
    for (int e = 0; e < NE; ++e) {          // ascending e: jax stable tie order
        float m = acc[e];
        int   mi = e;
#pragma unroll
        for (int q = 0; q < TK; ++q) {
            const bool  cx = m > tv[q];
            const float nt = cx ? m     : tv[q];
            const float nm = cx ? tv[q] : m;
            const int   ni = cx ? mi    : ti[q];
            const int   nj = cx ? ti[q] : mi;
            tv[q] = nt; m = nm; ti[q] = ni; mi = nj;
        }
    }

    const float mx = tv[0];
    float ex[TK];
    float s = 0.0f;
#pragma unroll
    for (int q = 0; q < TK; ++q) { ex[q] = __expf(tv[q] - mx); s += ex[q]; }
    const float rs = 1.0f / (s + 1e-20f);

    const size_t gt = (size_t)token * TK;
    float2* ip = (float2*)(oidx + gt);
    float2* wp = (float2*)(ow + gt);
    ip[0] = make_float2((float)ti[0], (float)ti[1]);
    ip[1] = make_float2((float)ti[2], (float)ti[3]);
    ip[2] = make_float2((float)ti[4], (float)ti[5]);
    wp[0] = make_float2(ex[0]*rs, ex[1]*rs);
    wp[1] = make_float2(ex[2]*rs, ex[3]*rs);
    wp[2] = make_float2(ex[4]*rs, ex[5]*rs);

#pragma unroll
    for (int q = 0; q < TK; ++q) atomicAdd(&cnt_s[ti[q]], 1u);

    // full softmax probs in place (for aux-loss Pi)
    float Z = 0.0f;
#pragma unroll
    for (int e = 0; e < NE; ++e) { acc[e] = __expf(acc[e] - mx); Z += acc[e]; }
    const float rz = 1.0f / Z;
#pragma unroll
    for (int e = 0; e < NE; ++e) acc[e] *= rz;
}

__global__ __launch_bounds__(BLK, 2)
void gate_kernel(const float* __restrict__ X,
                 const float* __restrict__ W,
                 float* __restrict__ oidx,
                 float* __restrict__ ow,
                 float* __restrict__ Pi_g,
                 unsigned int* __restrict__ cnt_g)
{
    // Experts 32..63 in LDS, column-rotated: Wt[k][col], col=(e'+4*((k>>2)&7))&31.
    // Hot-loop reads are wave-uniform (single address -> never conflict); the
    // rotation only de-conflicts the one-time staging stores (4-way there).
    __shared__ float        Wt[HID][WCOL];   // 16 KB
    __shared__ float        Pi_s[NE];
    __shared__ unsigned int cnt_s[NE];

    const int tid  = threadIdx.x;
    const int lane = tid & 63;

    if (tid < NE) { Pi_s[tid] = 0.0f; cnt_s[tid] = 0u; }

    // ---- stage experts 32..63 -> LDS (one-time)
    {
        const float4* W4 = (const float4*)W;
#pragma unroll
        for (int i = 0; i < 4; ++i) {
            const int flat = tid + i * BLK;        // [0,1024) float4 of upper half
            const float4 v = W4[1024 + flat];
            const int e   = flat >> 5;             // local expert 0..31
            const int k0  = (flat & 31) << 2;
            const int col = (e + ((flat & 7) << 2)) & 31;
            Wt[k0+0][col] = v.x; Wt[k0+1][col] = v.y;
            Wt[k0+2][col] = v.z; Wt[k0+3][col] = v.w;
        }
    }
    __syncthreads();

    const int tokenA = blockIdx.x * (BLK * TPT) + tid;
    const int tokenB = tokenA + BLK;
    const float4* xa4 = (const float4*)(X + (size_t)tokenA * HID);
    const float4* xb4 = (const float4*)(X + (size_t)tokenB * HID);

    float accA[NE], accB[NE];
#pragma unroll
    for (int e = 0; e < NE; ++e) { accA[e] = 0.0f; accB[e] = 0.0f; }

#pragma unroll 1
    for (int c = 0; c < 8; ++c) {          // k-chunks of 16
        float xA[16], xB[16];
#pragma unroll
        for (int j = 0; j < 4; ++j) {
            const float4 va = xa4[c*4 + j];
            xA[4*j+0] = va.x; xA[4*j+1] = va.y; xA[4*j+2] = va.z; xA[4*j+3] = va.w;
            const float4 vb = xb4[c*4 + j];
            xB[4*j+0] = vb.x; xB[4*j+1] = vb.y; xB[4*j+2] = vb.z; xB[4*j+3] = vb.w;
        }

        // ---- experts 0..31: scalar path (16 KB slab, K$-resident, SGPR operands)
        const float* wb = W + c * 16;      // + e*HID + kk  (wave-uniform)
#pragma unroll
        for (int e0 = 0; e0 < 32; e0 += 4) {
#pragma unroll
            for (int kk = 0; kk < 16; ++kk) {
#pragma unroll
                for (int j = 0; j < 4; ++j) {
                    const float wv = wb[(e0 + j) * HID + kk];
                    accA[e0+j] = fmaf(xA[kk], wv, accA[e0+j]);
                    accB[e0+j] = fmaf(xB[kk], wv, accB[e0+j]);
                }
            }
        }

        // ---- experts 32..63: LDS path (uniform ds_read_b128 broadcast)
#pragma unroll
        for (int kk = 0; kk < 16; ++kk) {
            const int row = c*16 + kk;
            const int rot = (row >> 2) & 7;                 // compile-time
            const float4* wrow = (const float4*)&Wt[row][0];
#pragma unroll
            for (int q = 0; q < 8; ++q) {
                const float4 w = wrow[(q + rot) & 7];       // experts 32+4q..+3
                const int eb = 32 + 4*q;
                accA[eb+0] = fmaf(xA[kk], w.x, accA[eb+0]);
                accA[eb+1] = fmaf(xA[kk], w.y, accA[eb+1]);
                accA[eb+2] = fmaf(xA[kk], w.z, accA[eb+2]);
                accA[eb+3] = fmaf(xA[kk], w.w, accA[eb+3]);
                accB[eb+0] = fmaf(xB[kk], w.x, accB[eb+0]);
                accB[eb+1] = fmaf(xB[kk], w.y, accB[eb+1]);
                accB[eb+2] = fmaf(xB[kk], w.z, accB[eb+2]);
                accB[eb+3] = fmaf(xB[kk], w.w, accB[eb+3]);
            }
        }
    }

    // ---- per-token epilogues (acc arrays become softmax probs)
    epilogue(accA, tokenA, oidx, ow, cnt_s);
    epilogue(accB, tokenB, oidx, ow, cnt_s);

    // ---- Pi: merge both tokens, 63-shuffle recursive-halving transpose-reduce
#pragma unroll
    for (int e = 0; e < NE; ++e) accA[e] += accB[e];

#pragma unroll
    for (int s = 32; s >= 1; s >>= 1) {
        const bool up = (lane & s) != 0;
#pragma unroll
        for (int i = 0; i < s; ++i) {
            const float lo = accA[i], hi = accA[i + s];
            const float send = up ? lo : hi;
            const float recv = __shfl_xor(send, s);
            accA[i] = (up ? hi : lo) + recv;
        }
    }
    atomicAdd(&Pi_s[lane], accA[0]);

    __syncthreads();
    if (tid < NE) {
        atomicAdd(&Pi_g[tid], Pi_s[tid]);
        atomicAdd(&cnt_g[tid], cnt_s[tid]);
    }
}

__global__ void aux_kernel(const float* __restrict__ Pi_g,
                           const unsigned int* __restrict__ cnt_g,
                           float* __restrict__ out_aux)
{
    const int e = threadIdx.x;   // 64 threads
    const float Pi = Pi_g[e] * (1.0f / (float)NTOK);
    const float ce = (float)cnt_g[e] * (1.0f / (float)(NTOK * TK));
    float v = Pi * ce * (float)NE;
#pragma unroll
    for (int off = 32; off > 0; off >>= 1) v += __shfl_down(v, off);
    if (e == 0) out_aux[0] = v * 1.0e-3f;
}

extern "C" void kernel_launch(void* const* d_in, const int* in_sizes, int n_in,
                              void* d_out, int out_size, void* d_ws, size_t ws_size,
                              hipStream_t stream) {
    const float* X = (const float*)d_in[0];
    const float* W = (const float*)d_in[1];

    float* out  = (float*)d_out;
    float* oidx = out;                          // N*6 indices (as float)
    float* ow   = out + (size_t)NTOK * TK;      // N*6 weights
    float* aux  = out + (size_t)NTOK * TK * 2;  // 1 scalar

    float*        Pi_g  = (float*)d_ws;
    unsigned int* cnt_g = (unsigned int*)((char*)d_ws + 256);

    hipMemsetAsync(d_ws, 0, 512, stream);
    gate_kernel<<<GRID, BLK, 0, stream>>>(X, W, oidx, ow, Pi_g, cnt_g);
    aux_kernel<<<1, 64, 0, stream>>>(Pi_g, cnt_g, aux);
}

// Round 7
// 257.808 us; speedup vs baseline: 1.9782x; 1.9782x over previous
//
#include <hip/hip_runtime.h>
#include <cfloat>

#define NTOK (64 * 4096)   // 262144 tokens
#define HID  128
#define NE   64
#define TK   6
#define BLK  256
#define TPB  256           // tokens per block
#define GRID (NTOK / TPB)  // 1024 blocks
#define LST  67            // logit row stride: 67%32=3 coprime -> b32 conflict-free

__global__ __launch_bounds__(BLK, 2)
void gate_kernel(const float* __restrict__ X,
                 const float* __restrict__ W,
                 float* __restrict__ oidx,
                 float* __restrict__ ow,
                 float* __restrict__ Pi_g,
                 unsigned int* __restrict__ cnt_g)
{
    // Phase GEMM: smem[0..8192)   = W rotated: Wlds[k][(e + 4*((k>>2)&15)) & 63]
    // Phase EPI : smem[0..256*67) = logits L[t][e] at t*LST+e (overlay after barrier)
    __shared__ float        smem[TPB * LST];   // 68.6 KB
    __shared__ float        mz[2 * TPB];
    __shared__ float        Pi_s[NE];
    __shared__ unsigned int cnt_s[NE];

    const int tid  = threadIdx.x;
    const int lane = tid & 63;
    const int wv   = __builtin_amdgcn_readfirstlane(tid >> 6);  // 0..3
    const int eb   = wv * 16;                  // this wave's 16 experts

    if (tid < NE) cnt_s[tid] = 0u;

    // ---- stage W rotated (one-time; minor 4-way conflicts, negligible)
    {
        const float4* W4 = (const float4*)W;
#pragma unroll
        for (int i = 0; i < 8; ++i) {
            const int flat = tid + i * BLK;     // [0,2048) float4 index
            const float4 v = W4[flat];
            const int e   = flat >> 5;
            const int c   = flat & 31;          // k>>2
            const int col = (e + ((c & 15) << 2)) & 63;
            float* p = &smem[c * 256 + col];    // k rows 4c..4c+3
            p[0]   = v.x;
            p[64]  = v.y;
            p[128] = v.z;
            p[192] = v.w;
        }
    }
    __syncthreads();

    const int gtok0 = blockIdx.x * TPB;
    const float4* xr0 = (const float4*)(X + (size_t)(gtok0 + lane      ) * HID);
    const float4* xr1 = (const float4*)(X + (size_t)(gtok0 + lane +  64) * HID);
    const float4* xr2 = (const float4*)(X + (size_t)(gtok0 + lane + 128) * HID);
    const float4* xr3 = (const float4*)(X + (size_t)(gtok0 + lane + 192) * HID);

    float acc[4][16];
#pragma unroll
    for (int g = 0; g < 4; ++g)
#pragma unroll
        for (int j = 0; j < 16; ++j) acc[g][j] = 0.0f;

    // ---- GEMM: wave computes 16 experts x 256 tokens (4 tokens/lane)
#pragma unroll 2
    for (int c = 0; c < 32; ++c) {             // k = 4c..4c+3
        float xs[4][4];
        {
            const float4 v0 = xr0[c], v1 = xr1[c], v2 = xr2[c], v3 = xr3[c];
            xs[0][0]=v0.x; xs[0][1]=v0.y; xs[0][2]=v0.z; xs[0][3]=v0.w;
            xs[1][0]=v1.x; xs[1][1]=v1.y; xs[1][2]=v1.z; xs[1][3]=v1.w;
            xs[2][0]=v2.x; xs[2][1]=v2.y; xs[2][2]=v2.z; xs[2][3]=v2.w;
            xs[3][0]=v3.x; xs[3][1]=v3.y; xs[3][2]=v3.z; xs[3][3]=v3.w;
        }
        const int rr = (c & 15) << 2;
        const int c0 = (eb +  0 + rr) & 63;
        const int c1 = (eb +  4 + rr) & 63;
        const int c2 = (eb +  8 + rr) & 63;
        const int c3 = (eb + 12 + rr) & 63;
        const float* rowb = &smem[c * 256];
#pragma unroll
        for (int d = 0; d < 4; ++d) {
            const float* row = rowb + d * 64;
            const float4 w0 = *(const float4*)&row[c0];   // uniform: no conflicts
            const float4 w1 = *(const float4*)&row[c1];
            const float4 w2 = *(const float4*)&row[c2];
            const float4 w3 = *(const float4*)&row[c3];
#pragma unroll
            for (int g = 0; g < 4; ++g) {
                const float xv = xs[g][d];
                acc[g][ 0] = fmaf(xv, w0.x, acc[g][ 0]);
                acc[g][ 1] = fmaf(xv, w0.y, acc[g][ 1]);
                acc[g][ 2] = fmaf(xv, w0.z, acc[g][ 2]);
                acc[g][ 3] = fmaf(xv, w0.w, acc[g][ 3]);
                acc[g][ 4] = fmaf(xv, w1.x, acc[g][ 4]);
                acc[g][ 5] = fmaf(xv, w1.y, acc[g][ 5]);
                acc[g][ 6] = fmaf(xv, w1.z, acc[g][ 6]);
                acc[g][ 7] = fmaf(xv, w1.w, acc[g][ 7]);
                acc[g][ 8] = fmaf(xv, w2.x, acc[g][ 8]);
                acc[g][ 9] = fmaf(xv, w2.y, acc[g][ 9]);
                acc[g][10] = fmaf(xv, w2.z, acc[g][10]);
                acc[g][11] = fmaf(xv, w2.w, acc[g][11]);
                acc[g][12] = fmaf(xv, w3.x, acc[g][12]);
                acc[g][13] = fmaf(xv, w3.y, acc[g][13]);
                acc[g][14] = fmaf(xv, w3.z, acc[g][14]);
                acc[g][15] = fmaf(xv, w3.w, acc[g][15]);
            }
        }
    }

    __syncthreads();   // all waves done reading W -> overlay region with logits

    // ---- scatter logits: L[t][e] = smem[t*67 + e]; banks (3t+const)%32: conflict-free
#pragma unroll
    for (int g = 0; g < 4; ++g) {
        float* p = &smem[(lane + 64 * g) * LST + eb];
#pragma unroll
        for (int j = 0; j < 16; ++j) p[j] = acc[g][j];
    }
    __syncthreads();

    // ---- epilogue: thread = token (256 threads, 256 tokens)
    {
        const int t = tid;
        const float* Lrow = &smem[t * LST];
        float tv[TK]; int ti[TK];
#pragma unroll
        for (int q = 0; q < TK; ++q) { tv[q] = -FLT_MAX; ti[q] = 0; }

#pragma unroll 8
        for (int e = 0; e < NE; ++e) {         // ascending e: jax stable tie order
            float m = Lrow[e];                 // b32, conflict-free by stride design
            int   mi = e;
#pragma unroll
            for (int q = 0; q < TK; ++q) {
                const bool  cx = m > tv[q];
                const float nt = cx ? m     : tv[q];
                const float nm = cx ? tv[q] : m;
                const int   ni = cx ? mi    : ti[q];
                const int   nj = cx ? ti[q] : mi;
                tv[q] = nt; m = nm; ti[q] = ni; mi = nj;
            }
        }

        const float mx = tv[0];
        float ex[TK]; float s = 0.0f;
#pragma unroll
        for (int q = 0; q < TK; ++q) { ex[q] = __expf(tv[q] - mx); s += ex[q]; }
        const float rs = 1.0f / (s + 1e-20f);

        const size_t gt = (size_t)(gtok0 + t) * TK;
        float2* ip = (float2*)(oidx + gt);
        float2* wp = (float2*)(ow + gt);
        ip[0] = make_float2((float)ti[0], (float)ti[1]);
        ip[1] = make_float2((float)ti[2], (float)ti[3]);
        ip[2] = make_float2((float)ti[4], (float)ti[5]);
        wp[0] = make_float2(ex[0]*rs, ex[1]*rs);
        wp[1] = make_float2(ex[2]*rs, ex[3]*rs);
        wp[2] = make_float2(ex[4]*rs, ex[5]*rs);

#pragma unroll
        for (int q = 0; q < TK; ++q) atomicAdd(&cnt_s[ti[q]], 1u);

        float Z = 0.0f;
#pragma unroll 8
        for (int e = 0; e < NE; ++e) Z += __expf(Lrow[e] - mx);
        mz[2*t]     = mx;
        mz[2*t + 1] = 1.0f / Z;
    }
    __syncthreads();

    // ---- Pi: re-read logits in GEMM layout; lane's 4 tokens x wave's 16 experts
    {
        float pi[16];
#pragma unroll
        for (int j = 0; j < 16; ++j) pi[j] = 0.0f;
#pragma unroll
        for (int g = 0; g < 4; ++g) {
            const int t = lane + 64 * g;
            const float mxt = mz[2*t];
            const float rzt = mz[2*t + 1];
            const float* p = &smem[t * LST + eb];
#pragma unroll
            for (int j = 0; j < 16; ++j)
                pi[j] += __expf(p[j] - mxt) * rzt;
        }
        // butterfly: every lane ends with the wave-total for each of the 16 experts
#pragma unroll
        for (int s = 1; s <= 32; s <<= 1) {
#pragma unroll
            for (int j = 0; j < 16; ++j) pi[j] += __shfl_xor(pi[j], s);
        }
        if (lane < 16) Pi_s[eb + lane] = pi[lane];   // waves own disjoint experts
    }
    __syncthreads();

    if (tid < NE) {
        atomicAdd(&Pi_g[tid], Pi_s[tid]);
        atomicAdd(&cnt_g[tid], cnt_s[tid]);
    }
}

__global__ void aux_kernel(const float* __restrict__ Pi_g,
                           const unsigned int* __restrict__ cnt_g,
                           float* __restrict__ out_aux)
{
    const int e = threadIdx.x;   // 64 threads
    const float Pi = Pi_g[e] * (1.0f / (float)NTOK);
    const float ce = (float)cnt_g[e] * (1.0f / (float)(NTOK * TK));
    float v = Pi * ce * (float)NE;
#pragma unroll
    for (int off = 32; off > 0; off >>= 1) v += __shfl_down(v, off);
    if (e == 0) out_aux[0] = v * 1.0e-3f;
}

extern "C" void kernel_launch(void* const* d_in, const int* in_sizes, int n_in,
                              void* d_out, int out_size, void* d_ws, size_t ws_size,
                              hipStream_t stream) {
    const float* X = (const float*)d_in[0];
    const float* W = (const float*)d_in[1];

    float* out  = (float*)d_out;
    float* oidx = out;                          // N*6 indices (as float)
    float* ow   = out + (size_t)NTOK * TK;      // N*6 weights
    float* aux  = out + (size_t)NTOK * TK * 2;  // 1 scalar

    float*        Pi_g  = (float*)d_ws;
    unsigned int* cnt_g = (unsigned int*)((char*)d_ws + 256);

    hipMemsetAsync(d_ws, 0, 512, stream);
    gate_kernel<<<GRID, BLK, 0, stream>>>(X, W, oidx, ow, Pi_g, cnt_g);
    aux_kernel<<<1, 64, 0, stream>>>(Pi_g, cnt_g, aux);
}